// Round 2
// baseline (875.120 us; speedup 1.0000x reference)
//
#include <hip/hip_runtime.h>
#include <hip/hip_bf16.h>

#define N_BATCH 8
#define N_CH    16
#define N_SMP   480000
#define N_EARS  2
#define N_TAP   2048

#define NKT     65                    // K-tiles (of 32) per channel
#define ROWS    256                   // q-rows per block (16 samples each)
#define N_QROWS (N_SMP / 16)          // 30000
#define QB_PER_B ((N_QROWS + ROWS - 1) / ROWS)   // 118
#define XS_LEN  6400                  // LDS window samples (6160 needed + pad for dead loads)

typedef __bf16 bf16x8 __attribute__((ext_vector_type(8)));
typedef float  f32x4  __attribute__((ext_vector_type(4)));

// ---------------------------------------------------------------------------
// Prep: pack filters into MFMA-B-fragment order (Toeplitz arrangement).
// B[u][n] = h[e][c][2048 - u + n], u = kt*32 + quad*8 + j, n = lane&15.
// Flat: (((c*NKT + kt)*2 + e)*64 + lane)*8 + j  -> 16B/lane, coalesced.
// ---------------------------------------------------------------------------
__global__ void build_bpk(const float* __restrict__ h, __bf16* __restrict__ bpk)
{
    const int idx = blockIdx.x * 256 + threadIdx.x;
    const int total = N_CH * NKT * 2 * 64 * 8;
    if (idx >= total) return;

    const int j    = idx & 7;
    const int lane = (idx >> 3) & 63;
    const int e    = (idx >> 9) & 1;
    const int ckt  = idx >> 10;          // c*NKT + kt
    const int kt   = ckt % NKT;
    const int c    = ckt / NKT;

    const int n  = lane & 15;
    const int kq = (lane >> 4) * 8 + j;
    const int u  = kt * 32 + kq;
    const int k  = 2048 - u + n;

    float val = (k >= 0 && k < N_TAP) ? h[((long)e * N_CH + c) * N_TAP + k] : 0.0f;
    bpk[idx] = (__bf16)val;
}

// ---------------------------------------------------------------------------
// Main GEMM. Block = 256 thr (4 waves), covers 256 q-rows (4096 samples) of
// one batch. Wave wv owns 64 rows as 4 M-subtiles of 16; Toeplitz register
// window W[4][8] (fragments f(j), j = kt+8s) feeds all 4 msubs x 2 ears
// (8 MFMAs) from ONE ds_read_b128 per K-tile.
// ---------------------------------------------------------------------------
__global__ __launch_bounds__(256, 2)
void hoa_bin_gemm(const float* __restrict__ hoa,
                  const __bf16* __restrict__ bpk,
                  float* __restrict__ out)
{
    __shared__ __align__(16) __bf16 xs[XS_LEN];

    const int qb   = blockIdx.x;          // 0..117
    const int b    = blockIdx.y;          // 0..7
    const int tid  = threadIdx.x;
    const int lane = tid & 63;
    const int wv   = tid >> 6;            // wave 0..3
    const int mlan = lane & 15;
    const int quad = lane >> 4;

    const int q0 = qb * ROWS;
    const int t0 = 16 * q0 - 2048;        // sample index of xs[0] (>= -2048)

    const int abase = wv * 1024 + 16 * mlan + 8 * quad;   // A fragment base (elems)

    f32x4 acc[4][2] = {};                 // [msub][ear]

    for (int c = 0; c < N_CH; ++c) {
        __syncthreads();                  // previous channel's readers done

        // ---- stage channel c: fp32 global -> bf16 LDS window ----
        {
            const float* xc = hoa + ((long)(b * N_CH + c)) * N_SMP;
            for (int i = tid; i < XS_LEN / 4; i += 256) {
                const int t = t0 + 4 * i;
                float4 v = {0.f, 0.f, 0.f, 0.f};
                if (t >= 0 && t <= N_SMP - 4) v = *(const float4*)(xc + t);
                union { __bf16 hh[4]; uint2 u; } pk;
                pk.hh[0] = (__bf16)v.x; pk.hh[1] = (__bf16)v.y;
                pk.hh[2] = (__bf16)v.z; pk.hh[3] = (__bf16)v.w;
                *(uint2*)(&xs[4 * i]) = pk.u;
            }
        }
        __syncthreads();

        // ---- preload 32-fragment window: bank s holds f(8s .. 8s+7) ----
        bf16x8 W[4][8];
        #pragma unroll
        for (int s = 0; s < 4; ++s)
            #pragma unroll
            for (int i = 0; i < 8; ++i)
                W[s][i] = *(const bf16x8*)(&xs[abase + 32 * (8 * s + i)]);

        const __bf16* bp = bpk + (long)c * NKT * 1024 + lane * 8;

        // ---- 8 groups of 8 K-tiles; bank roles rotate with period 4 ----
        #pragma unroll
        for (int gg = 0; gg < 2; ++gg) {
            #pragma unroll
            for (int g4 = 0; g4 < 4; ++g4) {
                const int g = gg * 4 + g4;
                // compute 8 steps: kt = 8g+i ; msub s uses W[(g4+s)&3][i]
                #pragma unroll
                for (int i = 0; i < 8; ++i) {
                    const int kt = 8 * g + i;
                    bf16x8 b0 = *(const bf16x8*)(bp + kt * 1024);
                    bf16x8 b1 = *(const bf16x8*)(bp + kt * 1024 + 512);
                    #pragma unroll
                    for (int s = 0; s < 4; ++s) {
                        acc[s][0] = __builtin_amdgcn_mfma_f32_16x16x32_bf16(
                                        W[(g4 + s) & 3][i], b0, acc[s][0], 0, 0, 0);
                        acc[s][1] = __builtin_amdgcn_mfma_f32_16x16x32_bf16(
                                        W[(g4 + s) & 3][i], b1, acc[s][1], 0, 0, 0);
                    }
                }
                // refill retired bank g4 with f(8g+32 .. 8g+39)
                // (g=7 loads f(88..95): dead values, reads stay within XS_LEN pad)
                #pragma unroll
                for (int i = 0; i < 8; ++i)
                    W[g4][i] = *(const bf16x8*)(&xs[abase + 32 * (8 * g + 32 + i)]);
            }
        }

        // ---- tail kt = 64: msub s uses f(64+8s) = W[s][0] ----
        {
            bf16x8 b0 = *(const bf16x8*)(bp + 64 * 1024);
            bf16x8 b1 = *(const bf16x8*)(bp + 64 * 1024 + 512);
            #pragma unroll
            for (int s = 0; s < 4; ++s) {
                acc[s][0] = __builtin_amdgcn_mfma_f32_16x16x32_bf16(
                                W[s][0], b0, acc[s][0], 0, 0, 0);
                acc[s][1] = __builtin_amdgcn_mfma_f32_16x16x32_bf16(
                                W[s][0], b1, acc[s][1], 0, 0, 0);
            }
        }
    }

    // ---- epilogue: C/D layout row = quad*4 + r, col = lane&15 ----
    const long obase = (long)b * N_EARS * N_SMP;
    #pragma unroll
    for (int s = 0; s < 4; ++s) {
        #pragma unroll
        for (int e = 0; e < N_EARS; ++e) {
            #pragma unroll
            for (int r = 0; r < 4; ++r) {
                const int rl = wv * 64 + s * 16 + quad * 4 + r;
                const int q  = q0 + rl;
                if (q < N_QROWS) {
                    out[obase + (long)e * N_SMP + 16 * q + mlan] = acc[s][e][r];
                }
            }
        }
    }
}

// ---------------------------------------------------------------------------
extern "C" void kernel_launch(void* const* d_in, const int* in_sizes, int n_in,
                              void* d_out, int out_size, void* d_ws, size_t ws_size,
                              hipStream_t stream)
{
    const float* hoa = (const float*)d_in[0];   // [8,16,480000] fp32
    const float* h   = (const float*)d_in[1];   // [2,16,2048]  fp32
    float* out       = (float*)d_out;           // [8,2,480000] fp32
    __bf16* bpk      = (__bf16*)d_ws;           // 2,129,920 B filter pack

    const int total_bpk = N_CH * NKT * 2 * 64 * 8;          // 1,064,960
    build_bpk<<<(total_bpk + 255) / 256, 256, 0, stream>>>(h, bpk);

    dim3 grid(QB_PER_B, N_BATCH);
    hoa_bin_gemm<<<grid, 256, 0, stream>>>(hoa, bpk, out);
}

// Round 4
// 848.143 us; speedup vs baseline: 1.0318x; 1.0318x over previous
//
#include <hip/hip_runtime.h>
#include <hip/hip_bf16.h>

#define N_BATCH 8
#define N_CH    16
#define N_SMP   480000
#define N_EARS  2
#define N_TAP   2048

#define NKT     65                    // K-tiles (of 32) per channel
#define ROWS    256                   // q-rows per block (4 waves x 4 msubs x 16)
#define N_QROWS (N_SMP / 16)          // 30000
#define QB_PER_B ((N_QROWS + ROWS - 1) / ROWS)   // 118
#define XS_LEN  6400                  // bf16 elems per buffer (6160 real + pad for dead refills)
#define NF4     (XS_LEN / 4)          // 1600 float4 staging slots
#define BLK     256

typedef __bf16 bf16x8 __attribute__((ext_vector_type(8)));
typedef float  f32x4  __attribute__((ext_vector_type(4)));

// ---------------------------------------------------------------------------
// Prep: pack filters into MFMA-B-fragment order (verified rounds 1-2).
// B[u][n] = h[e][c][2048 - u + n], u = kt*32 + (lane>>4)*8 + j, n = lane&15.
// Flat: (((c*NKT + kt)*2 + e)*64 + lane)*8 + j  -> 16B/lane, coalesced.
// ---------------------------------------------------------------------------
__global__ void build_bpk(const float* __restrict__ h, __bf16* __restrict__ bpk)
{
    const int idx = blockIdx.x * 256 + threadIdx.x;
    const int total = N_CH * NKT * 2 * 64 * 8;
    if (idx >= total) return;

    const int j    = idx & 7;
    const int lane = (idx >> 3) & 63;
    const int e    = (idx >> 9) & 1;
    const int ckt  = idx >> 10;          // c*NKT + kt
    const int kt   = ckt % NKT;
    const int c    = ckt / NKT;

    const int n  = lane & 15;
    const int kq = (lane >> 4) * 8 + j;
    const int u  = kt * 32 + kq;
    const int k  = 2048 - u + n;

    float val = (k >= 0 && k < N_TAP) ? h[((long)e * N_CH + c) * N_TAP + k] : 0.0f;
    bpk[idx] = (__bf16)val;
}

// ---------------------------------------------------------------------------
// Main GEMM (round-2 verified math + depth-3 B prefetch + pipelined staging).
// Block = 256 thr (4 waves), 256 q-rows of one batch. Wave owns 64 rows as
// 4 msubs of 16; Toeplitz window W[4][8]: msub s at K-tile kt uses f(kt+8s),
// f(j) = xs[abase + 32j]. One ds_read_b128 + 2 prefetched global b128 feed
// 8 MFMAs per K-tile. K-loop is barrier-free -> vmcnt pipelining works.
// ---------------------------------------------------------------------------
__global__ __launch_bounds__(BLK, 2)
void hoa_bin_gemm(const float* __restrict__ hoa,
                  const __bf16* __restrict__ bpk,
                  float* __restrict__ out)
{
    __shared__ __align__(16) __bf16 xs[2][XS_LEN];

    const int qb   = blockIdx.x;          // 0..117
    const int b    = blockIdx.y;          // 0..7
    const int tid  = threadIdx.x;
    const int lane = tid & 63;
    const int wv   = tid >> 6;            // wave 0..3
    const int mlan = lane & 15;
    const int quad = lane >> 4;

    const int q0 = qb * ROWS;
    const int t0 = 16 * q0 - 2048;        // sample index of xs[.][0]

    const int abase = wv * 1024 + 16 * mlan + 8 * quad;

    const float* xb = hoa + (long)b * N_CH * N_SMP;

    f32x4 acc[4][2] = {};                 // [msub][ear]
    float4 sreg[7];

    // ---- prologue: stage channel 0 into xs[0] ----
    #pragma unroll
    for (int k = 0; k < 7; ++k) {
        const int i4 = tid + k * BLK;
        const int t  = t0 + 4 * i4;
        float4 v = {0.f, 0.f, 0.f, 0.f};
        if (i4 < NF4 && t >= 0 && t <= N_SMP - 4) v = *(const float4*)(xb + t);
        sreg[k] = v;
    }
    #pragma unroll
    for (int k = 0; k < 7; ++k) {
        const int i4 = tid + k * BLK;
        if (i4 < NF4) {
            union { __bf16 hh[4]; uint2 u; } pk;
            pk.hh[0] = (__bf16)sreg[k].x; pk.hh[1] = (__bf16)sreg[k].y;
            pk.hh[2] = (__bf16)sreg[k].z; pk.hh[3] = (__bf16)sreg[k].w;
            *(uint2*)(&xs[0][4 * i4]) = pk.u;
        }
    }

    for (int c = 0; c < N_CH; ++c) {
        __syncthreads();   // buf[c&1] staged; previous readers done

        const __bf16* xw = &xs[c & 1][0];
        const __bf16* bp = bpk + (long)c * (NKT * 1024) + lane * 8;

        // ---- prime B queue (depth 3) — oldest vmem ops, usable first ----
        bf16x8 BQ0[3], BQ1[3];
        #pragma unroll
        for (int d = 0; d < 3; ++d) {
            BQ0[d] = *(const bf16x8*)(bp + d * 1024);
            BQ1[d] = *(const bf16x8*)(bp + d * 1024 + 512);
        }

        // ---- issue staging loads for channel c+1 (consumed after compute) ----
        if (c + 1 < N_CH) {
            const float* xc = xb + (long)(c + 1) * N_SMP;
            #pragma unroll
            for (int k = 0; k < 7; ++k) {
                const int i4 = tid + k * BLK;
                const int t  = t0 + 4 * i4;
                float4 v = {0.f, 0.f, 0.f, 0.f};
                if (i4 < NF4 && t >= 0 && t <= N_SMP - 4) v = *(const float4*)(xc + t);
                sreg[k] = v;
            }
        }

        // ---- preload A window: bank s holds f(8s..8s+7) ----
        bf16x8 W[4][8];
        #pragma unroll
        for (int s = 0; s < 4; ++s)
            #pragma unroll
            for (int i = 0; i < 8; ++i)
                W[s][i] = *(const bf16x8*)(xw + abase + 32 * (8 * s + i));

        // ---- 8 fully-unrolled groups of 8 K-tiles ----
        #pragma unroll
        for (int g = 0; g < 8; ++g) {
            const int g4 = g & 3;
            #pragma unroll
            for (int i = 0; i < 8; ++i) {
                const int kt = 8 * g + i;
                const int d  = kt % 3;
                bf16x8 b0 = BQ0[d];
                bf16x8 b1 = BQ1[d];
                const int ktp = (kt + 3 <= 64) ? kt + 3 : 64;   // compile-time
                BQ0[d] = *(const bf16x8*)(bp + ktp * 1024);
                BQ1[d] = *(const bf16x8*)(bp + ktp * 1024 + 512);
                #pragma unroll
                for (int s = 0; s < 4; ++s) {
                    acc[s][0] = __builtin_amdgcn_mfma_f32_16x16x32_bf16(
                                    W[(g4 + s) & 3][i], b0, acc[s][0], 0, 0, 0);
                    acc[s][1] = __builtin_amdgcn_mfma_f32_16x16x32_bf16(
                                    W[(g4 + s) & 3][i], b1, acc[s][1], 0, 0, 0);
                }
            }
            // refill retired bank g4 with f(8g+32 .. 8g+39) (g=7: dead, in-pad)
            #pragma unroll
            for (int i = 0; i < 8; ++i)
                W[g4][i] = *(const bf16x8*)(xw + abase + 32 * (8 * g + 32 + i));
        }

        // ---- tail kt = 64: msub s uses f(64+8s) = bank s slot 0; BQ slot 64%3=1 ----
        {
            bf16x8 b0 = BQ0[1];
            bf16x8 b1 = BQ1[1];
            #pragma unroll
            for (int s = 0; s < 4; ++s) {
                acc[s][0] = __builtin_amdgcn_mfma_f32_16x16x32_bf16(
                                W[s][0], b0, acc[s][0], 0, 0, 0);
                acc[s][1] = __builtin_amdgcn_mfma_f32_16x16x32_bf16(
                                W[s][0], b1, acc[s][1], 0, 0, 0);
            }
        }

        // ---- write staged channel c+1 into the other buffer ----
        if (c + 1 < N_CH) {
            __bf16* xd = &xs[(c + 1) & 1][0];
            #pragma unroll
            for (int k = 0; k < 7; ++k) {
                const int i4 = tid + k * BLK;
                if (i4 < NF4) {
                    union { __bf16 hh[4]; uint2 u; } pk;
                    pk.hh[0] = (__bf16)sreg[k].x; pk.hh[1] = (__bf16)sreg[k].y;
                    pk.hh[2] = (__bf16)sreg[k].z; pk.hh[3] = (__bf16)sreg[k].w;
                    *(uint2*)(&xd[4 * i4]) = pk.u;
                }
            }
        }
    }

    // ---- epilogue: C/D layout row = quad*4 + r, col = lane&15 (verified) ----
    const long ob = (long)b * N_EARS * N_SMP;
    #pragma unroll
    for (int s = 0; s < 4; ++s) {
        #pragma unroll
        for (int e = 0; e < N_EARS; ++e) {
            #pragma unroll
            for (int r = 0; r < 4; ++r) {
                const int rl = wv * 64 + s * 16 + quad * 4 + r;
                const int q  = q0 + rl;
                if (q < N_QROWS)
                    out[ob + (long)e * N_SMP + 16 * q + mlan] = acc[s][e][r];
            }
        }
    }
}

// ---------------------------------------------------------------------------
extern "C" void kernel_launch(void* const* d_in, const int* in_sizes, int n_in,
                              void* d_out, int out_size, void* d_ws, size_t ws_size,
                              hipStream_t stream)
{
    const float* hoa = (const float*)d_in[0];   // [8,16,480000] fp32
    const float* h   = (const float*)d_in[1];   // [2,16,2048]  fp32
    float* out       = (float*)d_out;           // [8,2,480000] fp32
    __bf16* bpk      = (__bf16*)d_ws;           // 2,129,920 B filter pack

    const int total_bpk = N_CH * NKT * 2 * 64 * 8;          // 1,064,960
    build_bpk<<<(total_bpk + 255) / 256, 256, 0, stream>>>(h, bpk);

    dim3 grid(QB_PER_B, N_BATCH);
    hoa_bin_gemm<<<grid, BLK, 0, stream>>>(hoa, bpk, out);
}